// Round 2
// baseline (336.976 us; speedup 1.0000x reference)
//
#include <hip/hip_runtime.h>
#include <hip/hip_cooperative_groups.h>

namespace cg = cooperative_groups;

#define Hn 128
#define Ln 2048
#define NBn 64
#define K 64          // chunk length
#define G 32          // chunks: G*K == Ln
#define PITCH 65      // 64+1: bank (n+k)%32 per phase -> conflict-free b32
#define NTILES (Hn * G)   // 4096 (h,g) tiles

// Fused single-kernel version of the 3-phase w-space chunked scan.
// w = 2*C*z follows the same diagonal recurrence with input coeff 2*C*B;
// y_t = sum_n Re(w_n) + D*u_t; final z = w/(2C).
// Grid-strided over tiles so ANY co-resident block count works; grid size
// chosen host-side from the runtime's own occupancy calculator so the
// cooperative launch cannot fail the co-residency check (R1 failure mode).

__global__ __launch_bounds__(64, 2) void fused_scan(
    const float* __restrict__ u,
    const float* __restrict__ x_re, const float* __restrict__ x_im,
    const float* __restrict__ Lre,  const float* __restrict__ Lim,
    const float* __restrict__ Bre,  const float* __restrict__ Bim,
    const float* __restrict__ Cre,  const float* __restrict__ Cim,
    const float* __restrict__ Dv,   const int* __restrict__ dflag,
    float* __restrict__ out,
    float4* __restrict__ Sum,
    float2* __restrict__ Sin)
{
    __shared__ float g_s[K * PITCH];
    __shared__ float u_s[K];

    cg::grid_group grid = cg::this_grid();
    const int n    = threadIdx.x;
    const int nblk = gridDim.x;

    // ---------------- phase 1: local scans (grid-stride over tiles) ------
    for (int tile = blockIdx.x; tile < NTILES; tile += nblk) {
        const int h  = tile >> 5;      // tile / G
        const int g  = tile & 31;      // tile % G
        const int hn = h * NBn + n;
        const int l0 = g * K;

        __syncthreads();               // guard g_s/u_s reuse across tiles

        const float lre = Lre[hn], lim = Lim[hn];
        const float br  = Bre[hn], bi  = Bim[hn];
        const float cr  = Cre[hn], ci  = Cim[hn];
        const float Dh  = Dv[h];
        const float cbr2 = 2.f * (cr * br - ci * bi);   // 2*C*B
        const float cbi2 = 2.f * (cr * bi + ci * br);

        const float un = u[h * Ln + l0 + n];
        u_s[n] = un;
        const unsigned long long m = __ballot(dflag[l0 + n] != 0);
        __syncthreads();

        float wr = 0.f, wi = 0.f;
        if (m == 0ull) {               // reset-free chunk (~53%)
            #pragma unroll
            for (int k = 0; k < K; ++k) {
                const float uk = u_s[k];
                const float nr = fmaf(lre, wr, fmaf(-lim, wi, cbr2 * uk));
                const float ni = fmaf(lre, wi, fmaf( lim, wr, cbi2 * uk));
                wr = nr; wi = ni;
                g_s[k * PITCH + n] = wr;
            }
        } else {
            #pragma unroll
            for (int k = 0; k < K; ++k) {
                const bool  rs  = (m >> k) & 1ull;   // wave-uniform select
                const float lrk = rs ? 0.f : lre;
                const float lik = rs ? 0.f : lim;
                const float uk  = u_s[k];
                const float nr = fmaf(lrk, wr, fmaf(-lik, wi, cbr2 * uk));
                const float ni = fmaf(lrk, wi, fmaf( lik, wr, cbi2 * uk));
                wr = nr; wi = ni;
                g_s[k * PITCH + n] = wr;
            }
        }
        __syncthreads();

        // lane t sums row t: conflict-free b32 at PITCH 65
        const float* row = g_s + n * PITCH;
        float a0 = 0.f, a1 = 0.f, a2 = 0.f, a3 = 0.f;
        #pragma unroll
        for (int k = 0; k < NBn; k += 4) {
            a0 += row[k + 0]; a1 += row[k + 1];
            a2 += row[k + 2]; a3 += row[k + 3];
        }
        out[h * Ln + l0 + n] = (a0 + a1) + (a2 + a3) + Dh * un;

        // chunk summary: Lam^64 via 6 squarings, zeroed if any reset
        float pr = lre, pi = lim;
        #pragma unroll
        for (int it = 0; it < 6; ++it) {
            const float sr2 = pr * pr - pi * pi;
            const float si2 = 2.f * pr * pi;
            pr = sr2; pi = si2;
        }
        if (m) { pr = 0.f; pi = 0.f; }
        Sum[(h * G + g) * NBn + n] = make_float4(pr, pi, wr, wi);
    }

    grid.sync();

    // ---------------- phase 2: per-head serial combine -------------------
    for (int h2 = blockIdx.x; h2 < Hn; h2 += nblk) {
        const int hn2 = h2 * NBn + n;
        const float cr2 = Cre[hn2], ci2 = Cim[hn2];
        const float x0r = x_re[hn2], x0i = x_im[hn2];
        float sre = 2.f * (cr2 * x0r - ci2 * x0i);   // w-space initial state
        float sim = 2.f * (cr2 * x0i + ci2 * x0r);
        #pragma unroll
        for (int gg = 0; gg < G; ++gg) {
            const int idx = (h2 * G + gg) * NBn + n;
            const float4 s = Sum[idx];
            Sin[idx] = make_float2(sre, sim);
            const float nr = fmaf(s.x, sre, fmaf(-s.y, sim, s.z));
            const float ni = fmaf(s.x, sim, fmaf( s.y, sre, s.w));
            sre = nr; sim = ni;
        }
        const float c2r = 2.f * cr2, c2i = 2.f * ci2;   // z = w/(2C)
        const float inv = 1.f / (c2r * c2r + c2i * c2i);
        float* xlast = out + Hn * Ln;
        xlast[2 * hn2 + 0] = (sre * c2r + sim * c2i) * inv;
        xlast[2 * hn2 + 1] = (sim * c2r - sre * c2i) * inv;
    }

    grid.sync();

    // ---------------- phase 3: fixup (grid-stride over tiles) -------------
    for (int tile = blockIdx.x; tile < NTILES; tile += nblk) {
        const int h  = tile >> 5;
        const int g  = tile & 31;
        const int hn = h * NBn + n;
        const int l0 = g * K;

        __syncthreads();               // guard g_s reuse across tiles

        const float lre = Lre[hn], lim = Lim[hn];
        const float2 s = Sin[(h * G + g) * NBn + n];   // w_in

        const unsigned long long bal = __ballot(dflag[l0 + n] != 0);
        const int kr = bal ? (__ffsll((long long)bal) - 1) : K;

        const float l2r = fmaf(lre, lre, -lim * lim);  // Lam^2
        const float l2i = 2.f * lre * lim;

        float tAr = fmaf(lre, s.x, -lim * s.y);        // k=0: w_in*Lam
        float tAi = fmaf(lre, s.y,  lim * s.x);
        float tBr = fmaf(l2r, s.x, -l2i * s.y);        // k=1: w_in*Lam^2
        float tBi = fmaf(l2r, s.y,  l2i * s.x);
        g_s[0 * PITCH + n] = tAr;
        g_s[1 * PITCH + n] = tBr;
        #pragma unroll
        for (int k = 2; k < K; k += 2) {
            const float nAr = fmaf(l2r, tAr, -l2i * tAi);
            const float nAi = fmaf(l2r, tAi,  l2i * tAr);
            tAr = nAr; tAi = nAi;
            g_s[k * PITCH + n] = tAr;
            const float nBr = fmaf(l2r, tBr, -l2i * tBi);
            const float nBi = fmaf(l2r, tBi,  l2i * tBr);
            tBr = nBr; tBi = nBi;
            g_s[(k + 1) * PITCH + n] = tBr;
        }
        __syncthreads();

        const float* row = g_s + n * PITCH;
        float a0 = 0.f, a1 = 0.f, a2 = 0.f, a3 = 0.f;
        #pragma unroll
        for (int k = 0; k < NBn; k += 4) {
            a0 += row[k + 0]; a1 += row[k + 1];
            a2 += row[k + 2]; a3 += row[k + 3];
        }
        if (n < kr)
            out[h * Ln + l0 + n] += (a0 + a1) + (a2 + a3);
    }
}

// ---------------------------------------------------------------------------
// Fallback path: the proven 3-kernel pipeline (88.6 us baseline).
// ---------------------------------------------------------------------------
__global__ __launch_bounds__(64) void phase1_local(
    const float* __restrict__ u,
    const float* __restrict__ Lre,  const float* __restrict__ Lim,
    const float* __restrict__ Bre,  const float* __restrict__ Bim,
    const float* __restrict__ Cre,  const float* __restrict__ Cim,
    const float* __restrict__ Dv,   const int* __restrict__ dflag,
    float* __restrict__ out,
    float4* __restrict__ Sum)
{
    __shared__ float g_s[K * PITCH];
    __shared__ float u_s[K];

    const int g = blockIdx.x, h = blockIdx.y, n = threadIdx.x;
    const int hn = h * NBn + n;
    const int l0 = g * K;

    const float lre = Lre[hn], lim = Lim[hn];
    const float br  = Bre[hn], bi  = Bim[hn];
    const float cr  = Cre[hn], ci  = Cim[hn];
    const float Dh  = Dv[h];
    const float cbr2 = 2.f * (cr * br - ci * bi);
    const float cbi2 = 2.f * (cr * bi + ci * br);

    u_s[n] = u[h * Ln + l0 + n];
    const unsigned long long m = __ballot(dflag[l0 + n] != 0);
    __syncthreads();

    float wr = 0.f, wi = 0.f;
    if (m == 0ull) {
        #pragma unroll
        for (int k = 0; k < K; ++k) {
            const float uk = u_s[k];
            const float nr = fmaf(lre, wr, fmaf(-lim, wi, cbr2 * uk));
            const float ni = fmaf(lre, wi, fmaf( lim, wr, cbi2 * uk));
            wr = nr; wi = ni;
            g_s[k * PITCH + n] = wr;
        }
    } else {
        #pragma unroll
        for (int k = 0; k < K; ++k) {
            const bool  rs  = (m >> k) & 1ull;
            const float lrk = rs ? 0.f : lre;
            const float lik = rs ? 0.f : lim;
            const float uk  = u_s[k];
            const float nr = fmaf(lrk, wr, fmaf(-lik, wi, cbr2 * uk));
            const float ni = fmaf(lrk, wi, fmaf( lik, wr, cbi2 * uk));
            wr = nr; wi = ni;
            g_s[k * PITCH + n] = wr;
        }
    }
    __syncthreads();

    const float* row = g_s + n * PITCH;
    float a0 = 0.f, a1 = 0.f, a2 = 0.f, a3 = 0.f;
    #pragma unroll
    for (int k = 0; k < NBn; k += 4) {
        a0 += row[k + 0]; a1 += row[k + 1];
        a2 += row[k + 2]; a3 += row[k + 3];
    }
    out[h * Ln + l0 + n] = (a0 + a1) + (a2 + a3) + Dh * u_s[n];

    float pr = lre, pi = lim;
    #pragma unroll
    for (int it = 0; it < 6; ++it) {
        const float sr2 = pr * pr - pi * pi;
        const float si2 = 2.f * pr * pi;
        pr = sr2; pi = si2;
    }
    if (m) { pr = 0.f; pi = 0.f; }
    Sum[(h * G + g) * NBn + n] = make_float4(pr, pi, wr, wi);
}

__global__ __launch_bounds__(64) void phase2_combine(
    const float* __restrict__ x_re, const float* __restrict__ x_im,
    const float* __restrict__ Cre,  const float* __restrict__ Cim,
    const float4* __restrict__ Sum,
    float2* __restrict__ Sin,
    float* __restrict__ out)
{
    const int h = blockIdx.x, n = threadIdx.x;
    const int hn = h * NBn + n;
    const float cr = Cre[hn], ci = Cim[hn];
    const float x0r = x_re[hn], x0i = x_im[hn];
    float sre = 2.f * (cr * x0r - ci * x0i);
    float sim = 2.f * (cr * x0i + ci * x0r);
    #pragma unroll
    for (int g = 0; g < G; ++g) {
        const int idx = (h * G + g) * NBn + n;
        const float4 s = Sum[idx];
        Sin[idx] = make_float2(sre, sim);
        const float nr = fmaf(s.x, sre, fmaf(-s.y, sim, s.z));
        const float ni = fmaf(s.x, sim, fmaf( s.y, sre, s.w));
        sre = nr; sim = ni;
    }
    const float c2r = 2.f * cr, c2i = 2.f * ci;
    const float inv = 1.f / (c2r * c2r + c2i * c2i);
    float* xlast = out + Hn * Ln;
    xlast[2 * hn + 0] = (sre * c2r + sim * c2i) * inv;
    xlast[2 * hn + 1] = (sim * c2r - sre * c2i) * inv;
}

__global__ __launch_bounds__(64) void phase3_fixup(
    const float* __restrict__ Lre, const float* __restrict__ Lim,
    const int* __restrict__ dflag,
    const float2* __restrict__ Sin,
    float* __restrict__ out)
{
    __shared__ float g_s[K * PITCH];

    const int g = blockIdx.x, h = blockIdx.y, n = threadIdx.x;
    const int hn = h * NBn + n;
    const int l0 = g * K;

    const float2 s = Sin[(h * G + g) * NBn + n];
    const float lre = Lre[hn], lim = Lim[hn];

    const unsigned long long bal = __ballot(dflag[l0 + n] != 0);
    const int kr = bal ? (__ffsll((long long)bal) - 1) : K;

    const float l2r = lre * lre - lim * lim;
    const float l2i = 2.f * lre * lim;

    float tAr = fmaf(lre, s.x, -lim * s.y);
    float tAi = fmaf(lre, s.y,  lim * s.x);
    float tBr = fmaf(l2r, s.x, -l2i * s.y);
    float tBi = fmaf(l2r, s.y,  l2i * s.x);
    g_s[0 * PITCH + n] = tAr;
    g_s[1 * PITCH + n] = tBr;
    #pragma unroll
    for (int k = 2; k < K; k += 2) {
        const float nAr = fmaf(l2r, tAr, -l2i * tAi);
        const float nAi = fmaf(l2r, tAi,  l2i * tAr);
        tAr = nAr; tAi = nAi;
        g_s[k * PITCH + n] = tAr;
        const float nBr = fmaf(l2r, tBr, -l2i * tBi);
        const float nBi = fmaf(l2r, tBi,  l2i * tBr);
        tBr = nBr; tBi = nBi;
        g_s[(k + 1) * PITCH + n] = tBr;
    }
    __syncthreads();

    const float* row = g_s + n * PITCH;
    float a0 = 0.f, a1 = 0.f, a2 = 0.f, a3 = 0.f;
    #pragma unroll
    for (int k = 0; k < NBn; k += 4) {
        a0 += row[k + 0]; a1 += row[k + 1];
        a2 += row[k + 2]; a3 += row[k + 3];
    }
    if (n < kr)
        out[h * Ln + l0 + n] += (a0 + a1) + (a2 + a3);
}

extern "C" void kernel_launch(void* const* d_in, const int* in_sizes, int n_in,
                              void* d_out, int out_size, void* d_ws, size_t ws_size,
                              hipStream_t stream) {
    (void)in_sizes; (void)n_in; (void)out_size; (void)ws_size;
    const float* u    = (const float*)d_in[0];
    const float* x_re = (const float*)d_in[1];
    const float* x_im = (const float*)d_in[2];
    const float* Lre  = (const float*)d_in[3];
    const float* Lim  = (const float*)d_in[4];
    const float* Bre  = (const float*)d_in[5];
    const float* Bim  = (const float*)d_in[6];
    const float* Cre  = (const float*)d_in[7];
    const float* Cim  = (const float*)d_in[8];
    const float* Dv   = (const float*)d_in[9];
    const int*   dfl  = (const int*)d_in[10];
    float* out = (float*)d_out;

    const int HGN = Hn * G * NBn;          // 262144 entries
    float4* Sum = (float4*)d_ws;           // 4 MB
    float2* Sin = (float2*)(Sum + HGN);    // 2 MB

    // One-time capacity probe (host-only queries; graph-capture safe).
    // g_nblk > 0: cooperative grid size guaranteed co-resident by the
    // runtime's own occupancy model. g_nblk == -1: use 3-kernel fallback.
    static int g_nblk = -2;
    if (g_nblk == -2) {
        int dev = 0, coop = 0, cus = 0, occ = 0;
        if (hipGetDevice(&dev) == hipSuccess &&
            hipDeviceGetAttribute(&coop, hipDeviceAttributeCooperativeLaunch, dev) == hipSuccess &&
            coop != 0 &&
            hipDeviceGetAttribute(&cus, hipDeviceAttributeMultiprocessorCount, dev) == hipSuccess &&
            cus > 0 &&
            hipOccupancyMaxActiveBlocksPerMultiprocessor(&occ, (const void*)fused_scan, 64, 0) == hipSuccess &&
            occ >= 1) {
            long cap = (long)occ * (long)cus;
            g_nblk = (int)(cap < 2048 ? cap : 2048);
            if (g_nblk < Hn) g_nblk = -1;   // need >=128 blocks for phase 2
        } else {
            g_nblk = -1;
        }
    }

    if (g_nblk > 0) {
        void* args[] = {
            (void*)&u, (void*)&x_re, (void*)&x_im, (void*)&Lre, (void*)&Lim,
            (void*)&Bre, (void*)&Bim, (void*)&Cre, (void*)&Cim, (void*)&Dv,
            (void*)&dfl, (void*)&out, (void*)&Sum, (void*)&Sin
        };
        hipError_t err = hipLaunchCooperativeKernel((const void*)fused_scan,
                                                    dim3(g_nblk), dim3(64),
                                                    args, 0, stream);
        if (err == hipSuccess) return;
        g_nblk = -1;   // cooperative path unusable; fall through permanently
    }

    dim3 grid(G, Hn);
    phase1_local<<<grid, 64, 0, stream>>>(u, Lre, Lim, Bre, Bim, Cre, Cim,
                                          Dv, dfl, out, Sum);
    phase2_combine<<<Hn, 64, 0, stream>>>(x_re, x_im, Cre, Cim, Sum, Sin, out);
    phase3_fixup<<<grid, 64, 0, stream>>>(Lre, Lim, dfl, Sin, out);
}

// Round 3
// 90.549 us; speedup vs baseline: 3.7215x; 3.7215x over previous
//
#include <hip/hip_runtime.h>

#define Hn 128
#define Ln 2048
#define NBn 64
#define K 64          // chunk length
#define G 32          // chunks: G*K == Ln
#define PITCH 65      // 64+1: bank (n+k)%32 per phase -> conflict-free b32

// R2 post-mortem: cooperative fusion = 417us (grid.sync ~150-200us each on
// 8 XCDs; VALUBusy 1.27% => real work ~5us). Reverted.
// R0 counters re-read: dur_us 88.6 = ~2x 40us harness poison-fills of the
// 256MiB workspace + ~7us of kernels. Theory: the fill re-poisons d_ws
// because we use it. This version uses ZERO workspace: Sum/Sin live in
// static __device__ globals (6 MB, fully rewritten every iteration before
// any read -> no cross-iteration state dependence).

__device__ float4 g_Sum[Hn * G * NBn];   // 4 MB: {A_re, A_im, b_re, b_im}
__device__ float2 g_Sin[Hn * G * NBn];   // 2 MB: incoming w-state per chunk

// ---------------------------------------------------------------------------
// Phase 1: per-(h,chunk) local w-space scan (s_in = 0).
// ---------------------------------------------------------------------------
__global__ __launch_bounds__(64) void phase1_local(
    const float* __restrict__ u,
    const float* __restrict__ Lre,  const float* __restrict__ Lim,
    const float* __restrict__ Bre,  const float* __restrict__ Bim,
    const float* __restrict__ Cre,  const float* __restrict__ Cim,
    const float* __restrict__ Dv,   const int* __restrict__ dflag,
    float* __restrict__ out)
{
    __shared__ float g_s[K * PITCH];
    __shared__ float u_s[K];

    const int g = blockIdx.x, h = blockIdx.y, n = threadIdx.x;
    const int hn = h * NBn + n;
    const int l0 = g * K;

    const float lre = Lre[hn], lim = Lim[hn];
    const float br  = Bre[hn], bi  = Bim[hn];
    const float cr  = Cre[hn], ci  = Cim[hn];
    const float Dh  = Dv[h];
    const float cbr2 = 2.f * (cr * br - ci * bi);   // 2*C*B
    const float cbi2 = 2.f * (cr * bi + ci * br);

    u_s[n] = u[h * Ln + l0 + n];
    const unsigned long long m = __ballot(dflag[l0 + n] != 0);
    __syncthreads();

    float wr = 0.f, wi = 0.f;
    if (m == 0ull) {                 // reset-free chunk (~53% of chunks)
        #pragma unroll
        for (int k = 0; k < K; ++k) {
            const float uk = u_s[k];               // LDS broadcast (DS pipe)
            const float nr = fmaf(lre, wr, fmaf(-lim, wi, cbr2 * uk));
            const float ni = fmaf(lre, wi, fmaf( lim, wr, cbi2 * uk));
            wr = nr; wi = ni;
            g_s[k * PITCH + n] = wr;               // only Re needed for y
        }
    } else {
        #pragma unroll
        for (int k = 0; k < K; ++k) {
            const bool  rs  = (m >> k) & 1ull;     // wave-uniform select
            const float lrk = rs ? 0.f : lre;
            const float lik = rs ? 0.f : lim;
            const float uk  = u_s[k];
            const float nr = fmaf(lrk, wr, fmaf(-lik, wi, cbr2 * uk));
            const float ni = fmaf(lrk, wi, fmaf( lik, wr, cbi2 * uk));
            wr = nr; wi = ni;
            g_s[k * PITCH + n] = wr;
        }
    }
    __syncthreads();

    // lane t sums row t (timestep l0+t): conflict-free b32 at PITCH 65
    const float* row = g_s + n * PITCH;
    float a0 = 0.f, a1 = 0.f, a2 = 0.f, a3 = 0.f;
    #pragma unroll
    for (int k = 0; k < NBn; k += 4) {
        a0 += row[k + 0]; a1 += row[k + 1];
        a2 += row[k + 2]; a3 += row[k + 3];
    }
    out[h * Ln + l0 + n] = (a0 + a1) + (a2 + a3) + Dh * u_s[n];

    // chunk summary: Lam^64 via 6 squarings, zeroed if any reset in chunk
    float pr = lre, pi = lim;
    #pragma unroll
    for (int it = 0; it < 6; ++it) {
        const float sr2 = pr * pr - pi * pi;
        const float si2 = 2.f * pr * pi;
        pr = sr2; pi = si2;
    }
    if (m) { pr = 0.f; pi = 0.f; }
    g_Sum[(h * G + g) * NBn + n] = make_float4(pr, pi, wr, wi);
}

// ---------------------------------------------------------------------------
// Phase 2: per-head serial combine in w-space.
// ---------------------------------------------------------------------------
__global__ __launch_bounds__(64) void phase2_combine(
    const float* __restrict__ x_re, const float* __restrict__ x_im,
    const float* __restrict__ Cre,  const float* __restrict__ Cim,
    float* __restrict__ out)
{
    const int h = blockIdx.x, n = threadIdx.x;
    const int hn = h * NBn + n;
    const float cr = Cre[hn], ci = Cim[hn];
    const float x0r = x_re[hn], x0i = x_im[hn];
    float sre = 2.f * (cr * x0r - ci * x0i);    // w-space initial state
    float sim = 2.f * (cr * x0i + ci * x0r);
    #pragma unroll
    for (int g = 0; g < G; ++g) {
        const int idx = (h * G + g) * NBn + n;
        const float4 s = g_Sum[idx];
        g_Sin[idx] = make_float2(sre, sim);
        const float nr = fmaf(s.x, sre, fmaf(-s.y, sim, s.z));
        const float ni = fmaf(s.x, sim, fmaf( s.y, sre, s.w));
        sre = nr; sim = ni;
    }
    const float c2r = 2.f * cr, c2i = 2.f * ci; // z = w/(2C)
    const float inv = 1.f / (c2r * c2r + c2i * c2i);
    float* xlast = out + Hn * Ln;
    xlast[2 * hn + 0] = (sre * c2r + sim * c2i) * inv;
    xlast[2 * hn + 1] = (sim * c2r - sre * c2i) * inv;
}

// ---------------------------------------------------------------------------
// Phase 3: per-(h,chunk) correction, masked from the first reset onward.
// ---------------------------------------------------------------------------
__global__ __launch_bounds__(64) void phase3_fixup(
    const float* __restrict__ Lre, const float* __restrict__ Lim,
    const int* __restrict__ dflag,
    float* __restrict__ out)
{
    __shared__ float g_s[K * PITCH];

    const int g = blockIdx.x, h = blockIdx.y, n = threadIdx.x;
    const int hn = h * NBn + n;
    const int l0 = g * K;

    const float2 s = g_Sin[(h * G + g) * NBn + n];   // w_in
    const float lre = Lre[hn], lim = Lim[hn];

    const unsigned long long bal = __ballot(dflag[l0 + n] != 0);
    const int kr = bal ? (__ffsll((long long)bal) - 1) : K;

    const float l2r = lre * lre - lim * lim;       // Lam^2
    const float l2i = 2.f * lre * lim;

    float tAr = fmaf(lre, s.x, -lim * s.y);        // k=0: w_in*Lam
    float tAi = fmaf(lre, s.y,  lim * s.x);
    float tBr = fmaf(l2r, s.x, -l2i * s.y);        // k=1: w_in*Lam^2
    float tBi = fmaf(l2r, s.y,  l2i * s.x);
    g_s[0 * PITCH + n] = tAr;
    g_s[1 * PITCH + n] = tBr;
    #pragma unroll
    for (int k = 2; k < K; k += 2) {
        const float nAr = fmaf(l2r, tAr, -l2i * tAi);
        const float nAi = fmaf(l2r, tAi,  l2i * tAr);
        tAr = nAr; tAi = nAi;
        g_s[k * PITCH + n] = tAr;
        const float nBr = fmaf(l2r, tBr, -l2i * tBi);
        const float nBi = fmaf(l2r, tBi,  l2i * tBr);
        tBr = nBr; tBi = nBi;
        g_s[(k + 1) * PITCH + n] = tBr;
    }
    __syncthreads();

    const float* row = g_s + n * PITCH;
    float a0 = 0.f, a1 = 0.f, a2 = 0.f, a3 = 0.f;
    #pragma unroll
    for (int k = 0; k < NBn; k += 4) {
        a0 += row[k + 0]; a1 += row[k + 1];
        a2 += row[k + 2]; a3 += row[k + 3];
    }
    if (n < kr)
        out[h * Ln + l0 + n] += (a0 + a1) + (a2 + a3);
}

extern "C" void kernel_launch(void* const* d_in, const int* in_sizes, int n_in,
                              void* d_out, int out_size, void* d_ws, size_t ws_size,
                              hipStream_t stream) {
    (void)in_sizes; (void)n_in; (void)out_size; (void)d_ws; (void)ws_size;
    const float* u    = (const float*)d_in[0];
    const float* x_re = (const float*)d_in[1];
    const float* x_im = (const float*)d_in[2];
    const float* Lre  = (const float*)d_in[3];
    const float* Lim  = (const float*)d_in[4];
    const float* Bre  = (const float*)d_in[5];
    const float* Bim  = (const float*)d_in[6];
    const float* Cre  = (const float*)d_in[7];
    const float* Cim  = (const float*)d_in[8];
    const float* Dv   = (const float*)d_in[9];
    const int*   dfl  = (const int*)d_in[10];
    float* out = (float*)d_out;

    dim3 grid(G, Hn);
    phase1_local<<<grid, 64, 0, stream>>>(u, Lre, Lim, Bre, Bim, Cre, Cim,
                                          Dv, dfl, out);
    phase2_combine<<<Hn, 64, 0, stream>>>(x_re, x_im, Cre, Cim, out);
    phase3_fixup<<<grid, 64, 0, stream>>>(Lre, Lim, dfl, out);
}